// Round 6
// baseline (259.737 us; speedup 1.0000x reference)
//
#include <hip/hip_runtime.h>
#include <hip/hip_bf16.h>

// NRI edge-MLP encoder, fused single kernel (NO workspace):
// out[b,e,:] = relu(concat(x[b,send(e)], x[b,recv(e)]) @ W1^T + b1) @ W2^T + b2
// B=8, N=256, E=65280, n_in=64, n_hid=128, n_out=64.
// edge e: recv = e/255, k = e%255, send = k + (k >= recv)
//
// Round-6: 32x32x16 MFMA version. Round-5 was latency-bound with the LDS pipe
// as the largest per-CU resource (192 ds_read_b128/wave, +1cyc conflict each =
// counter 1.567M exactly). 32x32x16 halves W-fragment reads/edge AND MFMA
// instructions/edge (one b128 read feeds a 32-edge MFMA).
//  - phase 1: Ht = W1 @ E^T (+b1, relu). A = W1 rows from LDS, B = edge feats
//    from global (converted in-lane). C: col=lane&31=edge, row=(r&3)+8(r>>2)+4hi.
//  - pi trick at 32x32: W2 stored at permuted k-position p:
//    pi(16ks+8hi+j) = 32(ks>>1)+16(ks&1)+8(j>>2)+(j&3)+4hi. Then phase-2
//    B-frag[ks] = regs [8*(ks&1) .. +8) of acc[ks>>1] -- pure in-lane repack.
//  - biases: transient f32x4 global loads (L1-hot) with asm-opaqued pointers
//    (defeats LICM; resident biases were 48+ VGPRs).
//  - f32->bf16 via __float2bfloat16 (RNE, hw cvt) instead of 5-op bit-twiddle.
// LDS = 32K(W1) + 16K(W2-pi) = 48KB -> 3 blocks/CU; target VGPR <= 170 (3/SIMD).

using frag_t  = __attribute__((ext_vector_type(8))) short;           // 8 bf16 = 4 VGPRs
using f32x4   = __attribute__((ext_vector_type(4))) float;
using f32x16  = __attribute__((ext_vector_type(16))) float;
using ushort8 = __attribute__((ext_vector_type(8))) unsigned short;

__device__ inline unsigned short f2bf(float f) {
    union { __hip_bfloat16 h; unsigned short u; } v;
    v.h = __float2bfloat16(f);          // RNE, hardware cvt on gfx950
    return v.u;
}

__device__ inline ushort8 pack8(f32x4 a, f32x4 b) {
    ushort8 o;
    o[0] = f2bf(a[0]); o[1] = f2bf(a[1]); o[2] = f2bf(a[2]); o[3] = f2bf(a[3]);
    o[4] = f2bf(b[0]); o[5] = f2bf(b[1]); o[6] = f2bf(b[2]); o[7] = f2bf(b[3]);
    return o;
}

__device__ inline frag_t packfrag(f32x4 a, f32x4 b) {
    union { ushort8 u; frag_t f; } v; v.u = pack8(a, b); return v.f;
}

// 16B-chunk XOR swizzle (same proven scheme as rounds 0-5; bijective per row).
__device__ inline int swz(int row, int c) { return c ^ (row & 7); }

// grid 2040 = 8 batches x 255 blocks x 256 edges; wave owns 64 edges
// (2 groups of 32). One __syncthreads after cooperative W staging.
__global__ __launch_bounds__(256)
void nri_mlp_fused(const float* __restrict__ x,
                   const float* __restrict__ W1,
                   const float* __restrict__ b1,
                   const float* __restrict__ W2,
                   const float* __restrict__ b2,
                   float* __restrict__ out) {
    __shared__ unsigned short W1s[128 * 128];    // 32 KB, swizzled bf16 (plain k-chunks)
    __shared__ unsigned short W2s[64 * 128];     // 16 KB, pi-permuted + swizzled bf16

    const int tid  = threadIdx.x;
    const int wave = tid >> 6;
    const int lane = tid & 63;
    const int hi   = lane >> 5;                  // half-wave index
    const int l5   = lane & 31;

    const int bx = blockIdx.x;
    const int b  = bx / 255;
    const int eb = (bx - b * 255) * 256;
    const int e0 = eb + wave * 64;               // this wave's 64 edges

    const float* xb = x + b * (256 * 64);

    // ---- cooperative W1 stage: data k-chunk c of row r at slot swz(r,c) ----
    #pragma unroll
    for (int i = 0; i < 8; ++i) {                // 2048 chunks / 256 thr
        int cid  = tid + i * 256;
        int row  = cid >> 4;                     // 0..127 (hid)
        int c    = cid & 15;
        const float* s = W1 + row * 128 + c * 8;
        *(ushort8*)&W1s[row * 128 + swz(row, c) * 8] =
            pack8(*(const f32x4*)s, *(const f32x4*)(s + 4));
    }
    // ---- W2 stage at PERMUTED positions: position-chunk c holds hids
    // base+{0..3, 8..11}, base = 32(c>>2) + 16((c>>1)&1) + 4(c&1) ----
    #pragma unroll
    for (int i = 0; i < 4; ++i) {                // 1024 chunks / 256 thr
        int cid  = tid + i * 256;
        int row  = cid >> 4;                     // 0..63 (out-feat)
        int c    = cid & 15;
        int base = 32 * (c >> 2) + 16 * ((c >> 1) & 1) + 4 * (c & 1);
        const float* s = W2 + row * 128 + base;
        *(ushort8*)&W2s[row * 128 + swz(row, c) * 8] =
            pack8(*(const f32x4*)s, *(const f32x4*)(s + 8));
    }
    __syncthreads();

    #pragma unroll 1   // contain register pressure: no cross-group hoisting
    for (int g = 0; g < 2; ++g) {
        // this lane's edge (col = l5 in BOTH phases)
        int e    = e0 + g * 32 + l5;
        int recv = e / 255;
        int kk   = e - recv * 255;
        int send = kk + (kk >= recv ? 1 : 0);

        // ---- B-operand: af[ks] = edge feats k = 16ks + 8hi + (0..7) ----
        frag_t af[8];
        #pragma unroll
        for (int ks = 0; ks < 8; ++ks) {
            int node = (ks < 4) ? send : recv;           // k<64 <=> sender
            const float* s = xb + node * 64 + (ks & 3) * 16 + hi * 8;
            af[ks] = packfrag(*(const f32x4*)s, *(const f32x4*)(s + 4));
        }

        // ---- phase 1: Ht = W1 @ E^T. A = W1 rows streamed from LDS ----
        f32x16 acc[4];
        #pragma unroll
        for (int cb = 0; cb < 4; ++cb)
            #pragma unroll
            for (int r = 0; r < 16; ++r) acc[cb][r] = 0.f;
        #pragma unroll
        for (int ks = 0; ks < 8; ++ks) {
            int chunk = 2 * ks + hi;
            #pragma unroll
            for (int cb = 0; cb < 4; ++cb) {
                int row = 32 * cb + l5;
                frag_t w1 = *(const frag_t*)&W1s[row * 128 + swz(row, chunk) * 8];
                acc[cb] = __builtin_amdgcn_mfma_f32_32x32x16_bf16(w1, af[ks], acc[cb], 0, 0, 0);
            }
        }

        // ---- bias + relu + in-lane repack to phase-2 B-frags ----
        // acc[cb] reg r holds hid = 32cb + (r&3) + 8(r>>2) + 4hi;
        // hf[2cb+s] = packed regs [8s..8s+8) -- matches pi by construction.
        const float* b1p = b1;
        asm volatile("" : "+s"(b1p));    // opaque per iteration: no LICM residency
        frag_t hf[8];
        #pragma unroll
        for (int cb = 0; cb < 4; ++cb) {
            f32x4 t[4];
            #pragma unroll
            for (int m = 0; m < 4; ++m) {
                f32x4 bv = *(const f32x4*)(b1p + 32 * cb + 8 * m + 4 * hi);
                #pragma unroll
                for (int q = 0; q < 4; ++q) {
                    float v = acc[cb][4 * m + q] + bv[q];
                    t[m][q] = v > 0.f ? v : 0.f;
                }
            }
            hf[2 * cb]     = packfrag(t[0], t[1]);
            hf[2 * cb + 1] = packfrag(t[2], t[3]);
        }

        // ---- phase 2: out^T = W2 @ H^T, k in pi-order on both operands ----
        f32x16 acc2[2];
        #pragma unroll
        for (int c2 = 0; c2 < 2; ++c2)
            #pragma unroll
            for (int r = 0; r < 16; ++r) acc2[c2][r] = 0.f;
        #pragma unroll
        for (int ks = 0; ks < 8; ++ks) {
            int chunk = 2 * ks + hi;
            #pragma unroll
            for (int c2 = 0; c2 < 2; ++c2) {
                int row = 32 * c2 + l5;
                frag_t w2 = *(const frag_t*)&W2s[row * 128 + swz(row, chunk) * 8];
                acc2[c2] = __builtin_amdgcn_mfma_f32_32x32x16_bf16(w2, hf[ks], acc2[c2], 0, 0, 0);
            }
        }

        // ---- b2 + store: acc2[c2] reg r -> out-feat 32c2 + (r&3) + 8(r>>2) + 4hi ----
        const float* b2p = b2;
        asm volatile("" : "+s"(b2p));
        float* ob = out + ((long)b * 65280 + e) * 64;
        #pragma unroll
        for (int c2 = 0; c2 < 2; ++c2) {
            #pragma unroll
            for (int m = 0; m < 4; ++m) {
                f32x4 bv = *(const f32x4*)(b2p + 32 * c2 + 8 * m + 4 * hi);
                f32x4 v;
                #pragma unroll
                for (int q = 0; q < 4; ++q) v[q] = acc2[c2][4 * m + q] + bv[q];
                *(f32x4*)&ob[32 * c2 + 8 * m + 4 * hi] = v;
            }
        }
    }
}

extern "C" void kernel_launch(void* const* d_in, const int* in_sizes, int n_in,
                              void* d_out, int out_size, void* d_ws, size_t ws_size,
                              hipStream_t stream) {
    const float* x  = (const float*)d_in[0];
    // d_in[1] = rel_rec, d_in[2] = rel_send: one-hot incidence, replaced by index math
    const float* W1 = (const float*)d_in[3];
    const float* b1 = (const float*)d_in[4];
    const float* W2 = (const float*)d_in[5];
    const float* b2 = (const float*)d_in[6];
    (void)d_ws; (void)ws_size; (void)in_sizes; (void)n_in; (void)out_size;
    float* out = (float*)d_out;

    nri_mlp_fused<<<2040, 256, 0, stream>>>(x, W1, b1, W2, b2, out);
}

// Round 7
// 238.138 us; speedup vs baseline: 1.0907x; 1.0907x over previous
//
#include <hip/hip_runtime.h>
#include <hip/hip_bf16.h>

// NRI edge-MLP encoder, fused single kernel (NO workspace):
// out[b,e,:] = relu(concat(x[b,send(e)], x[b,recv(e)]) @ W1^T + b1) @ W2^T + b2
// B=8, N=256, E=65280, n_in=64, n_hid=128, n_out=64.
// edge e: recv = e/255, k = e%255, send = k + (k >= recv)
//
// Round-7: kill scattered VMEM. R5/R6 both sat at ~80us with all pipes idle
// and wave lifetime ~37k cyc for ~3k cyc of work -> TA/L1 address-divergence
// bound: the af gather (64 distinct lines per wave-load, 256B lane stride)
// and the out stores (same scatter) serialize on the CU's VMEM front-end.
//  (1) x staged per-block into LDS (coalesced global reads, bf16, swizzled);
//      af becomes ds_read_b128 (send 4-way swz, recv broadcast). Also removes
//      128 cvt/lane (convert once at staging).
//  (2) phase 2 operands SWAPPED: mfma(hf, w2). Same pi, same W2s layout, same
//      in-lane repack (algebra: pi(16ks+8hi+j)=32(ks>>1)+16(ks&1)+8(j>>2)+
//      (j&3)+4hi; hf[ks]=regs[8(ks&1)..+8) of acc[ks>>1]), but C flips to
//      col=out-feat, row=edge -> stores are 128B-contiguous per half-wave
//      (2-4 lines/instr instead of 64). b2 = 2 resident floats.
// LDS = 32K(W1) + 16K(W2-pi) + 32K(X) = 80 KB dynamic -> 2 blocks/CU.
// Blocks widen to 384 thr (6 waves): grid 1360, 12 waves/CU.

using frag_t  = __attribute__((ext_vector_type(8))) short;           // 8 bf16 = 4 VGPRs
using f32x4   = __attribute__((ext_vector_type(4))) float;
using f32x16  = __attribute__((ext_vector_type(16))) float;
using ushort8 = __attribute__((ext_vector_type(8))) unsigned short;

__device__ inline unsigned short f2bf(float f) {
    union { __hip_bfloat16 h; unsigned short u; } v;
    v.h = __float2bfloat16(f);          // RNE, hardware cvt on gfx950
    return v.u;
}

__device__ inline ushort8 pack8(f32x4 a, f32x4 b) {
    ushort8 o;
    o[0] = f2bf(a[0]); o[1] = f2bf(a[1]); o[2] = f2bf(a[2]); o[3] = f2bf(a[3]);
    o[4] = f2bf(b[0]); o[5] = f2bf(b[1]); o[6] = f2bf(b[2]); o[7] = f2bf(b[3]);
    return o;
}

__device__ inline frag_t packfrag(f32x4 a, f32x4 b) {
    union { ushort8 u; frag_t f; } v; v.u = pack8(a, b); return v.f;
}

// grid 1360 = 8 batches x 170 blocks x 384 edges; wave owns 64 edges
// (2 groups of 32). One __syncthreads after cooperative staging.
__global__ __launch_bounds__(384)
void nri_mlp_fused(const float* __restrict__ x,
                   const float* __restrict__ W1,
                   const float* __restrict__ b1,
                   const float* __restrict__ W2,
                   const float* __restrict__ b2,
                   float* __restrict__ out) {
    extern __shared__ unsigned short smem[];
    unsigned short* W1s = smem;                        // 128x128 bf16 = 32 KB
    unsigned short* W2s = smem + 128 * 128;            //  64x128 bf16 = 16 KB (pi-permuted)
    unsigned short* Xs  = smem + 128 * 128 + 64 * 128; // 256x 64 bf16 = 32 KB

    const int tid  = threadIdx.x;
    const int wave = tid >> 6;
    const int lane = tid & 63;
    const int hi   = lane >> 5;                  // half-wave index
    const int l5   = lane & 31;

    const int bx = blockIdx.x;
    const int b  = bx / 170;
    const int eb = (bx - b * 170) * 384;
    const int e0 = eb + wave * 64;               // this wave's 64 edges

    const float* xb = x + b * (256 * 64);

    // ---- cooperative staging (all coalesced global reads) ----
    // W1: data k-chunk c of row r at slot c^(r&7). 2048 chunks.
    #pragma unroll
    for (int i = 0; i < 6; ++i) {
        int cid = tid + i * 384;
        if (cid < 2048) {
            int row = cid >> 4, c = cid & 15;
            const float* s = W1 + row * 128 + c * 8;
            *(ushort8*)&W1s[row * 128 + (c ^ (row & 7)) * 8] =
                pack8(*(const f32x4*)s, *(const f32x4*)(s + 4));
        }
    }
    // W2 at PERMUTED positions: position-chunk c holds hids base+{0..3,8..11},
    // base = 32(c>>2) + 16((c>>1)&1) + 4(c&1). 1024 chunks.
    #pragma unroll
    for (int i = 0; i < 3; ++i) {
        int cid = tid + i * 384;
        if (cid < 1024) {
            int row = cid >> 4, c = cid & 15;
            int base = 32 * (c >> 2) + 16 * ((c >> 1) & 1) + 4 * (c & 1);
            const float* s = W2 + row * 128 + base;
            *(ushort8*)&W2s[row * 128 + (c ^ (row & 7)) * 8] =
                pack8(*(const f32x4*)s, *(const f32x4*)(s + 8));
        }
    }
    // X: node rows of 8 chunks, chunk c at slot c^(node&7). 2048 chunks.
    #pragma unroll
    for (int i = 0; i < 6; ++i) {
        int cid = tid + i * 384;
        if (cid < 2048) {
            int node = cid >> 3, c = cid & 7;
            const float* s = xb + node * 64 + c * 8;
            *(ushort8*)&Xs[node * 64 + (c ^ (node & 7)) * 8] =
                pack8(*(const f32x4*)s, *(const f32x4*)(s + 4));
        }
    }
    __syncthreads();

    float b2v[2] = { b2[l5], b2[32 + l5] };      // flipped layout: 2 resident floats

    #pragma unroll 1   // contain register pressure: no cross-group hoisting
    for (int g = 0; g < 2; ++g) {
        // this lane's edge for gather / phase-1 (col = l5)
        int e    = e0 + g * 32 + l5;
        int recv = e / 255;
        int kk   = e - recv * 255;
        int send = kk + (kk >= recv ? 1 : 0);

        // ---- B-operand from LDS: af[ks] = edge feats k = 16ks + 8hi + (0..7) ----
        frag_t af[8];
        #pragma unroll
        for (int ks = 0; ks < 8; ++ks) {
            int node = (ks < 4) ? send : recv;           // k<64 <=> sender
            int c    = (ks & 3) * 2 + hi;
            af[ks] = *(const frag_t*)&Xs[node * 64 + (c ^ (node & 7)) * 8];
        }

        // ---- phase 1: Ht = W1 @ E^T. A = W1 rows streamed from LDS ----
        f32x16 acc[4];
        #pragma unroll
        for (int cb = 0; cb < 4; ++cb)
            #pragma unroll
            for (int r = 0; r < 16; ++r) acc[cb][r] = 0.f;
        #pragma unroll
        for (int ks = 0; ks < 8; ++ks) {
            int chunk = 2 * ks + hi;
            #pragma unroll
            for (int cb = 0; cb < 4; ++cb) {
                int row = 32 * cb + l5;
                frag_t w1 = *(const frag_t*)&W1s[row * 128 + (chunk ^ (row & 7)) * 8];
                acc[cb] = __builtin_amdgcn_mfma_f32_32x32x16_bf16(w1, af[ks], acc[cb], 0, 0, 0);
            }
        }

        // ---- bias + relu + in-lane repack (pi trick, unchanged) ----
        // acc[cb] reg r holds hid = 32cb + (r&3) + 8(r>>2) + 4hi;
        // hf[2cb+s] = packed regs [8s..8s+8).
        const float* b1p = b1;
        asm volatile("" : "+s"(b1p));    // opaque per iteration: no LICM residency
        frag_t hf[8];
        #pragma unroll
        for (int cb = 0; cb < 4; ++cb) {
            f32x4 t[4];
            #pragma unroll
            for (int m = 0; m < 4; ++m) {
                f32x4 bv = *(const f32x4*)(b1p + 32 * cb + 8 * m + 4 * hi);
                #pragma unroll
                for (int q = 0; q < 4; ++q) {
                    float v = acc[cb][4 * m + q] + bv[q];
                    t[m][q] = v > 0.f ? v : 0.f;
                }
            }
            hf[2 * cb]     = packfrag(t[0], t[1]);
            hf[2 * cb + 1] = packfrag(t[2], t[3]);
        }

        // ---- phase 2 FLIPPED: out = H @ W2^T. A = hf (edges), B = W2s (pi-order) ----
        f32x16 acc2[2];
        #pragma unroll
        for (int c2 = 0; c2 < 2; ++c2)
            #pragma unroll
            for (int r = 0; r < 16; ++r) acc2[c2][r] = 0.f;
        #pragma unroll
        for (int ks = 0; ks < 8; ++ks) {
            int chunk = 2 * ks + hi;
            #pragma unroll
            for (int c2 = 0; c2 < 2; ++c2) {
                int row = 32 * c2 + l5;
                frag_t w2 = *(const frag_t*)&W2s[row * 128 + (chunk ^ (row & 7)) * 8];
                acc2[c2] = __builtin_amdgcn_mfma_f32_32x32x16_bf16(hf[ks], w2, acc2[c2], 0, 0, 0);
            }
        }

        // ---- store: col = l5 = out-feat (+32c2), reg r -> edge (r&3)+8(r>>2)+4hi.
        // Per instruction: two 128B-contiguous runs -> 2-4 cache lines (coalesced).
        float* ob = out + ((long)b * 65280 + e0 + g * 32) * 64;
        #pragma unroll
        for (int c2 = 0; c2 < 2; ++c2) {
            #pragma unroll
            for (int r = 0; r < 16; ++r) {
                int eo = (r & 3) + 8 * (r >> 2) + 4 * hi;
                ob[eo * 64 + 32 * c2 + l5] = acc2[c2][r] + b2v[c2];
            }
        }
    }
}

extern "C" void kernel_launch(void* const* d_in, const int* in_sizes, int n_in,
                              void* d_out, int out_size, void* d_ws, size_t ws_size,
                              hipStream_t stream) {
    const float* x  = (const float*)d_in[0];
    // d_in[1] = rel_rec, d_in[2] = rel_send: one-hot incidence, replaced by index math
    const float* W1 = (const float*)d_in[3];
    const float* b1 = (const float*)d_in[4];
    const float* W2 = (const float*)d_in[5];
    const float* b2 = (const float*)d_in[6];
    (void)d_ws; (void)ws_size; (void)in_sizes; (void)n_in; (void)out_size;
    float* out = (float*)d_out;

    static bool attr_set = false;
    if (!attr_set) {
        hipFuncSetAttribute(reinterpret_cast<const void*>(nri_mlp_fused),
                            hipFuncAttributeMaxDynamicSharedMemorySize, 81920);
        attr_set = true;
    }
    nri_mlp_fused<<<1360, 384, 81920, stream>>>(x, W1, b1, W2, b2, out);
}

// Round 8
// 228.400 us; speedup vs baseline: 1.1372x; 1.0426x over previous
//
#include <hip/hip_runtime.h>
#include <hip/hip_bf16.h>

// NRI edge-MLP encoder, fused single kernel (NO workspace):
// out[b,e,:] = relu(concat(x[b,send(e)], x[b,recv(e)]) @ W1^T + b1) @ W2^T + b2
// B=8, N=256, E=65280, n_in=64, n_hid=128, n_out=64.
// edge e: recv = e/255, k = e%255, send = k + (k >= recv)
//
// Round-8: occupancy + staging amortization. R7 (scatter-free) is ~59us
// (dur_us - 178.8us fixed harness fills) with every pipe <30% busy and R6's
// measured occupancy 19% (~6 eff waves/CU): latency-bound at low occupancy.
// This round: 512-thr blocks (8 waves), wave owns 128 edges (4 groups of 32)
// -> block = 1024 edges, grid = 8 x 64 = 512 = EXACTLY 2 blocks/CU, both
// co-resident (LDS 2x80K = 160K, threads 2x512, VGPR capped 128 via
// __launch_bounds__(512,4); compiler used 88 in R6/R7 so no spill risk).
// 16 steady waves/CU (+33%), clean 2-round schedule, staging amortized
// 2.67x, block A's compute overlaps block B's staging. MFMA/pi/store
// machinery byte-identical to R7:
//  - x staged per-block into LDS bf16 swizzled; af = ds_read_b128.
//  - phase 1: Ht = W1 @ E^T (A = W1 rows from LDS). C: col=l5=edge.
//  - pi trick: W2 stored at permuted k-pos; phase-2 B-frag = in-lane repack
//    of phase-1 acc regs (no cross-lane, no H traffic).
//  - phase 2 flipped: out = H @ W2^T -> stores 128B-contiguous per half-wave.

using frag_t  = __attribute__((ext_vector_type(8))) short;           // 8 bf16 = 4 VGPRs
using f32x4   = __attribute__((ext_vector_type(4))) float;
using f32x16  = __attribute__((ext_vector_type(16))) float;
using ushort8 = __attribute__((ext_vector_type(8))) unsigned short;

__device__ inline unsigned short f2bf(float f) {
    union { __hip_bfloat16 h; unsigned short u; } v;
    v.h = __float2bfloat16(f);          // RNE, hardware cvt on gfx950
    return v.u;
}

__device__ inline ushort8 pack8(f32x4 a, f32x4 b) {
    ushort8 o;
    o[0] = f2bf(a[0]); o[1] = f2bf(a[1]); o[2] = f2bf(a[2]); o[3] = f2bf(a[3]);
    o[4] = f2bf(b[0]); o[5] = f2bf(b[1]); o[6] = f2bf(b[2]); o[7] = f2bf(b[3]);
    return o;
}

__device__ inline frag_t packfrag(f32x4 a, f32x4 b) {
    union { ushort8 u; frag_t f; } v; v.u = pack8(a, b); return v.f;
}

// grid 512 = 8 batches x 64 blocks x 1024 edges; 8 waves/block, wave owns
// 128 edges (4 groups of 32). Last block per batch is partial (768 edges),
// handled by a wave-uniform group guard (65280 % 32 == 0 -> no ragged lanes).
__global__ __launch_bounds__(512, 4)
void nri_mlp_fused(const float* __restrict__ x,
                   const float* __restrict__ W1,
                   const float* __restrict__ b1,
                   const float* __restrict__ W2,
                   const float* __restrict__ b2,
                   float* __restrict__ out) {
    extern __shared__ unsigned short smem[];
    unsigned short* W1s = smem;                        // 128x128 bf16 = 32 KB
    unsigned short* W2s = smem + 128 * 128;            //  64x128 bf16 = 16 KB (pi-permuted)
    unsigned short* Xs  = smem + 128 * 128 + 64 * 128; // 256x 64 bf16 = 32 KB

    const int tid  = threadIdx.x;
    const int wave = tid >> 6;                   // 0..7
    const int lane = tid & 63;
    const int hi   = lane >> 5;                  // half-wave index
    const int l5   = lane & 31;

    const int bx = blockIdx.x;
    const int b  = bx >> 6;                      // batch
    const int eb = (bx & 63) * 1024;             // block's first edge
    const int e0 = eb + wave * 128;              // this wave's first edge

    const float* xb = x + b * (256 * 64);

    // ---- cooperative staging (all coalesced global reads) ----
    // W1: data k-chunk c of row r at slot c^(r&7). 2048 chunks / 512 thr.
    #pragma unroll
    for (int i = 0; i < 4; ++i) {
        int cid = tid + i * 512;
        int row = cid >> 4, c = cid & 15;
        const float* s = W1 + row * 128 + c * 8;
        *(ushort8*)&W1s[row * 128 + (c ^ (row & 7)) * 8] =
            pack8(*(const f32x4*)s, *(const f32x4*)(s + 4));
    }
    // W2 at PERMUTED positions: position-chunk c holds hids base+{0..3,8..11},
    // base = 32(c>>2) + 16((c>>1)&1) + 4(c&1). 1024 chunks / 512 thr.
    #pragma unroll
    for (int i = 0; i < 2; ++i) {
        int cid = tid + i * 512;
        int row = cid >> 4, c = cid & 15;
        int base = 32 * (c >> 2) + 16 * ((c >> 1) & 1) + 4 * (c & 1);
        const float* s = W2 + row * 128 + base;
        *(ushort8*)&W2s[row * 128 + (c ^ (row & 7)) * 8] =
            pack8(*(const f32x4*)s, *(const f32x4*)(s + 8));
    }
    // X: node rows of 8 chunks, chunk c at slot c^(node&7). 2048 chunks / 512 thr.
    #pragma unroll
    for (int i = 0; i < 4; ++i) {
        int cid = tid + i * 512;
        int node = cid >> 3, c = cid & 7;
        const float* s = xb + node * 64 + c * 8;
        *(ushort8*)&Xs[node * 64 + (c ^ (node & 7)) * 8] =
            pack8(*(const f32x4*)s, *(const f32x4*)(s + 4));
    }
    __syncthreads();

    float b2v[2] = { b2[l5], b2[32 + l5] };      // flipped layout: 2 resident floats

    #pragma unroll 1   // contain register pressure: no cross-group hoisting
    for (int g = 0; g < 4; ++g) {
        int ebase = e0 + g * 32;
        if (ebase >= 65280) break;               // partial-block guard (wave-uniform)

        // this lane's edge for gather / phase-1 (col = l5)
        int e    = ebase + l5;
        int recv = e / 255;
        int kk   = e - recv * 255;
        int send = kk + (kk >= recv ? 1 : 0);

        // ---- B-operand from LDS: af[ks] = edge feats k = 16ks + 8hi + (0..7) ----
        frag_t af[8];
        #pragma unroll
        for (int ks = 0; ks < 8; ++ks) {
            int node = (ks < 4) ? send : recv;           // k<64 <=> sender
            int c    = (ks & 3) * 2 + hi;
            af[ks] = *(const frag_t*)&Xs[node * 64 + (c ^ (node & 7)) * 8];
        }

        // ---- phase 1: Ht = W1 @ E^T. A = W1 rows streamed from LDS ----
        f32x16 acc[4];
        #pragma unroll
        for (int cb = 0; cb < 4; ++cb)
            #pragma unroll
            for (int r = 0; r < 16; ++r) acc[cb][r] = 0.f;
        #pragma unroll
        for (int ks = 0; ks < 8; ++ks) {
            int chunk = 2 * ks + hi;
            #pragma unroll
            for (int cb = 0; cb < 4; ++cb) {
                int row = 32 * cb + l5;
                frag_t w1 = *(const frag_t*)&W1s[row * 128 + (chunk ^ (row & 7)) * 8];
                acc[cb] = __builtin_amdgcn_mfma_f32_32x32x16_bf16(w1, af[ks], acc[cb], 0, 0, 0);
            }
        }

        // ---- bias + relu + in-lane repack (pi trick) ----
        // acc[cb] reg r holds hid = 32cb + (r&3) + 8(r>>2) + 4hi;
        // hf[2cb+s] = packed regs [8s..8s+8).
        const float* b1p = b1;
        asm volatile("" : "+s"(b1p));    // opaque per iteration: no LICM residency
        frag_t hf[8];
        #pragma unroll
        for (int cb = 0; cb < 4; ++cb) {
            f32x4 t[4];
            #pragma unroll
            for (int m = 0; m < 4; ++m) {
                f32x4 bv = *(const f32x4*)(b1p + 32 * cb + 8 * m + 4 * hi);
                #pragma unroll
                for (int q = 0; q < 4; ++q) {
                    float v = acc[cb][4 * m + q] + bv[q];
                    t[m][q] = v > 0.f ? v : 0.f;
                }
            }
            hf[2 * cb]     = packfrag(t[0], t[1]);
            hf[2 * cb + 1] = packfrag(t[2], t[3]);
        }

        // ---- phase 2 flipped: out = H @ W2^T. A = hf (edges), B = W2s (pi-order) ----
        f32x16 acc2[2];
        #pragma unroll
        for (int c2 = 0; c2 < 2; ++c2)
            #pragma unroll
            for (int r = 0; r < 16; ++r) acc2[c2][r] = 0.f;
        #pragma unroll
        for (int ks = 0; ks < 8; ++ks) {
            int chunk = 2 * ks + hi;
            #pragma unroll
            for (int c2 = 0; c2 < 2; ++c2) {
                int row = 32 * c2 + l5;
                frag_t w2 = *(const frag_t*)&W2s[row * 128 + (chunk ^ (row & 7)) * 8];
                acc2[c2] = __builtin_amdgcn_mfma_f32_32x32x16_bf16(hf[ks], w2, acc2[c2], 0, 0, 0);
            }
        }

        // ---- store: col = l5 = out-feat (+32c2), reg r -> edge (r&3)+8(r>>2)+4hi.
        // Per instruction: two 128B-contiguous runs (coalesced).
        float* ob = out + ((long)b * 65280 + ebase) * 64;
        #pragma unroll
        for (int c2 = 0; c2 < 2; ++c2) {
            #pragma unroll
            for (int r = 0; r < 16; ++r) {
                int eo = (r & 3) + 8 * (r >> 2) + 4 * hi;
                ob[eo * 64 + 32 * c2 + l5] = acc2[c2][r] + b2v[c2];
            }
        }
    }
}

extern "C" void kernel_launch(void* const* d_in, const int* in_sizes, int n_in,
                              void* d_out, int out_size, void* d_ws, size_t ws_size,
                              hipStream_t stream) {
    const float* x  = (const float*)d_in[0];
    // d_in[1] = rel_rec, d_in[2] = rel_send: one-hot incidence, replaced by index math
    const float* W1 = (const float*)d_in[3];
    const float* b1 = (const float*)d_in[4];
    const float* W2 = (const float*)d_in[5];
    const float* b2 = (const float*)d_in[6];
    (void)d_ws; (void)ws_size; (void)in_sizes; (void)n_in; (void)out_size;
    float* out = (float*)d_out;

    static bool attr_set = false;
    if (!attr_set) {
        hipFuncSetAttribute(reinterpret_cast<const void*>(nri_mlp_fused),
                            hipFuncAttributeMaxDynamicSharedMemorySize, 81920);
        attr_set = true;
    }
    nri_mlp_fused<<<512, 512, 81920, stream>>>(x, W1, b1, W2, b2, out);
}

// Round 9
// 221.820 us; speedup vs baseline: 1.1709x; 1.0297x over previous
//
#include <hip/hip_runtime.h>
#include <hip/hip_bf16.h>

// NRI edge-MLP encoder, fused single kernel (NO workspace):
// out[b,e,:] = relu(concat(x[b,send(e)], x[b,recv(e)]) @ W1^T + b1) @ W2^T + b2
// B=8, N=256, E=65280, n_in=64, n_hid=128, n_out=64.
// edge e: recv = e/255, k = e%255, send = k + (k >= recv)
//
// Round-9: guarantee 2-block/CU residency + shorten per-group critical path.
// R8 kernel ~49.6us ~= the SERIAL sum of LDS (21us) + HBM write (21us) +
// staging -- consistent with 2 blocks/CU running in serial rounds because
// the ~130-reg peak of the 4-acc structure brushed the 128 cap. Fix:
//  (a) per-cb pipeline: phase1(cb) -> relu/repack(cb) -> the 4 phase-2
//      MFMAs consuming hf[2cb],hf[2cb+1]. Only ONE f32x16 acc live (16
//      regs, was 64). Peak ~100 regs -> residency by construction.
//  (b) b1 folds into acc INIT (4 f32x4 loads at cb start, consumed 8
//      MFMAs later -> latency hidden; repack = pure relu+pack). Was a
//      mid-group global-load dependency on the critical path.
//  (c) phase-2 MFMAs interleave between cb sections: acc2 chain broken
//      up by independent phase-1 work, W2 reads spread out.
// Machinery unchanged: x/W1/W2 staged bf16+swizzled in LDS; pi-permuted
// W2s; phase-1 Ht = W1 @ E^T; in-lane repack; phase-2 out = H @ W2^T with
// coalesced half-wave stores. Grid 512 = 8b x 64blk x 1024 edges, 512 thr.

using frag_t  = __attribute__((ext_vector_type(8))) short;           // 8 bf16 = 4 VGPRs
using f32x4   = __attribute__((ext_vector_type(4))) float;
using f32x16  = __attribute__((ext_vector_type(16))) float;
using ushort8 = __attribute__((ext_vector_type(8))) unsigned short;

__device__ inline unsigned short f2bf(float f) {
    union { __hip_bfloat16 h; unsigned short u; } v;
    v.h = __float2bfloat16(f);          // RNE, hardware cvt on gfx950
    return v.u;
}

__device__ inline ushort8 pack8(f32x4 a, f32x4 b) {
    ushort8 o;
    o[0] = f2bf(a[0]); o[1] = f2bf(a[1]); o[2] = f2bf(a[2]); o[3] = f2bf(a[3]);
    o[4] = f2bf(b[0]); o[5] = f2bf(b[1]); o[6] = f2bf(b[2]); o[7] = f2bf(b[3]);
    return o;
}

__device__ inline frag_t packfrag(f32x4 a, f32x4 b) {
    union { ushort8 u; frag_t f; } v; v.u = pack8(a, b); return v.f;
}

// grid 512 = 8 batches x 64 blocks x 1024 edges; 8 waves/block, wave owns
// 128 edges (4 groups of 32). Last block per batch partial, wave-uniform guard.
__global__ __launch_bounds__(512, 4)
void nri_mlp_fused(const float* __restrict__ x,
                   const float* __restrict__ W1,
                   const float* __restrict__ b1,
                   const float* __restrict__ W2,
                   const float* __restrict__ b2,
                   float* __restrict__ out) {
    extern __shared__ unsigned short smem[];
    unsigned short* W1s = smem;                        // 128x128 bf16 = 32 KB
    unsigned short* W2s = smem + 128 * 128;            //  64x128 bf16 = 16 KB (pi-permuted)
    unsigned short* Xs  = smem + 128 * 128 + 64 * 128; // 256x 64 bf16 = 32 KB

    const int tid  = threadIdx.x;
    const int wave = tid >> 6;                   // 0..7
    const int lane = tid & 63;
    const int hi   = lane >> 5;                  // half-wave index
    const int l5   = lane & 31;

    const int bx = blockIdx.x;
    const int b  = bx >> 6;                      // batch
    const int eb = (bx & 63) * 1024;             // block's first edge
    const int e0 = eb + wave * 128;              // this wave's first edge

    const float* xb = x + b * (256 * 64);

    // ---- cooperative staging (all coalesced global reads) ----
    // W1: data k-chunk c of row r at slot c^(r&7). 2048 chunks / 512 thr.
    #pragma unroll
    for (int i = 0; i < 4; ++i) {
        int cid = tid + i * 512;
        int row = cid >> 4, c = cid & 15;
        const float* s = W1 + row * 128 + c * 8;
        *(ushort8*)&W1s[row * 128 + (c ^ (row & 7)) * 8] =
            pack8(*(const f32x4*)s, *(const f32x4*)(s + 4));
    }
    // W2 at PERMUTED positions: position-chunk c holds hids base+{0..3,8..11},
    // base = 32(c>>2) + 16((c>>1)&1) + 4(c&1). 1024 chunks / 512 thr.
    #pragma unroll
    for (int i = 0; i < 2; ++i) {
        int cid = tid + i * 512;
        int row = cid >> 4, c = cid & 15;
        int base = 32 * (c >> 2) + 16 * ((c >> 1) & 1) + 4 * (c & 1);
        const float* s = W2 + row * 128 + base;
        *(ushort8*)&W2s[row * 128 + (c ^ (row & 7)) * 8] =
            pack8(*(const f32x4*)s, *(const f32x4*)(s + 8));
    }
    // X: node rows of 8 chunks, chunk c at slot c^(node&7). 2048 chunks / 512 thr.
    #pragma unroll
    for (int i = 0; i < 4; ++i) {
        int cid = tid + i * 512;
        int node = cid >> 3, c = cid & 7;
        const float* s = xb + node * 64 + c * 8;
        *(ushort8*)&Xs[node * 64 + (c ^ (node & 7)) * 8] =
            pack8(*(const f32x4*)s, *(const f32x4*)(s + 4));
    }
    __syncthreads();

    float b2v[2] = { b2[l5], b2[32 + l5] };      // flipped layout: 2 resident floats

    #pragma unroll 1   // contain register pressure: no cross-group hoisting
    for (int g = 0; g < 4; ++g) {
        int ebase = e0 + g * 32;
        if (ebase >= 65280) break;               // partial-block guard (wave-uniform)

        // this lane's edge for gather / phase-1 (col = l5)
        int e    = ebase + l5;
        int recv = e / 255;
        int kk   = e - recv * 255;
        int send = kk + (kk >= recv ? 1 : 0);

        // ---- B-operand from LDS: af[ks] = edge feats k = 16ks + 8hi + (0..7) ----
        frag_t af[8];
        #pragma unroll
        for (int ks = 0; ks < 8; ++ks) {
            int node = (ks < 4) ? send : recv;           // k<64 <=> sender
            int c    = (ks & 3) * 2 + hi;
            af[ks] = *(const frag_t*)&Xs[node * 64 + (c ^ (node & 7)) * 8];
        }

        const float* b1p = b1;
        asm volatile("" : "+s"(b1p));    // opaque per group: no LICM residency

        f32x16 acc2[2];
        #pragma unroll
        for (int c2 = 0; c2 < 2; ++c2)
            #pragma unroll
            for (int r = 0; r < 16; ++r) acc2[c2][r] = 0.f;

        // ---- per-cb pipeline: phase1(cb) -> relu/repack -> phase2 partial ----
        #pragma unroll
        for (int cb = 0; cb < 4; ++cb) {
            // bias-init: acc reg 4m+q holds hid 32cb + 8m + 4hi + q
            f32x16 acc;
            #pragma unroll
            for (int m = 0; m < 4; ++m) {
                f32x4 bv = *(const f32x4*)(b1p + 32 * cb + 8 * m + 4 * hi);
                acc[4 * m + 0] = bv[0]; acc[4 * m + 1] = bv[1];
                acc[4 * m + 2] = bv[2]; acc[4 * m + 3] = bv[3];
            }
            // phase 1: Ht rows 32cb..+32 = W1 @ E^T (W1 streamed from LDS)
            #pragma unroll
            for (int ks = 0; ks < 8; ++ks) {
                int chunk = 2 * ks + hi;
                int row   = 32 * cb + l5;
                frag_t w1 = *(const frag_t*)&W1s[row * 128 + (chunk ^ (row & 7)) * 8];
                acc = __builtin_amdgcn_mfma_f32_32x32x16_bf16(w1, af[ks], acc, 0, 0, 0);
            }
            // relu + in-lane repack (pi trick): hf[2cb+s] = packed regs [8s..8s+8)
            f32x4 t[4];
            #pragma unroll
            for (int m = 0; m < 4; ++m)
                #pragma unroll
                for (int q = 0; q < 4; ++q) {
                    float v = acc[4 * m + q];
                    t[m][q] = v > 0.f ? v : 0.f;
                }
            frag_t hf0 = packfrag(t[0], t[1]);
            frag_t hf1 = packfrag(t[2], t[3]);
            // phase 2 partial: k-blocks ks2 = 2cb (hf0), 2cb+1 (hf1)
            #pragma unroll
            for (int s = 0; s < 2; ++s) {
                frag_t hf  = s ? hf1 : hf0;
                int chunk  = 2 * (2 * cb + s) + hi;
                #pragma unroll
                for (int c2 = 0; c2 < 2; ++c2) {
                    int row = 32 * c2 + l5;
                    frag_t w2 = *(const frag_t*)&W2s[row * 128 + (chunk ^ (row & 7)) * 8];
                    acc2[c2] = __builtin_amdgcn_mfma_f32_32x32x16_bf16(hf, w2, acc2[c2], 0, 0, 0);
                }
            }
        }

        // ---- store: col = l5 = out-feat (+32c2), reg r -> edge (r&3)+8(r>>2)+4hi.
        // Per instruction: two 128B-contiguous runs (coalesced).
        float* ob = out + ((long)b * 65280 + ebase) * 64;
        #pragma unroll
        for (int c2 = 0; c2 < 2; ++c2) {
            #pragma unroll
            for (int r = 0; r < 16; ++r) {
                int eo = (r & 3) + 8 * (r >> 2) + 4 * hi;
                ob[eo * 64 + 32 * c2 + l5] = acc2[c2][r] + b2v[c2];
            }
        }
    }
}

extern "C" void kernel_launch(void* const* d_in, const int* in_sizes, int n_in,
                              void* d_out, int out_size, void* d_ws, size_t ws_size,
                              hipStream_t stream) {
    const float* x  = (const float*)d_in[0];
    // d_in[1] = rel_rec, d_in[2] = rel_send: one-hot incidence, replaced by index math
    const float* W1 = (const float*)d_in[3];
    const float* b1 = (const float*)d_in[4];
    const float* W2 = (const float*)d_in[5];
    const float* b2 = (const float*)d_in[6];
    (void)d_ws; (void)ws_size; (void)in_sizes; (void)n_in; (void)out_size;
    float* out = (float*)d_out;

    static bool attr_set = false;
    if (!attr_set) {
        hipFuncSetAttribute(reinterpret_cast<const void*>(nri_mlp_fused),
                            hipFuncAttributeMaxDynamicSharedMemorySize, 81920);
        attr_set = true;
    }
    nri_mlp_fused<<<512, 512, 81920, stream>>>(x, W1, b1, W2, b2, out);
}